// Round 1
// baseline (924.509 us; speedup 1.0000x reference)
//
#include <hip/hip_runtime.h>
#include <hip/hip_bf16.h>
#include <cstdint>
#include <cstddef>

// tanh_max attention, B=4 H=12 S=2048 D=32, fp32 in/out. attn_mask is a
// faithful no-op in the reference -> never read.
//
// R5: register-pressure attack. Model says R4 (926us) is ~20x above every
// pipe roofline (~30-50us); prime suspect is VGPR spill under
// __launch_bounds__(256,6) (budget ~80, R4 live-set ~85-95).
//   - drop the V double-prefetch (v_nxt0/1): load V(c) directly at the top
//     of iteration c. Load->use distance to the PV MFMAs is still ~250 cyc
//     (readP + 16 transcendentals + ~30 VALU) -> covers L2 latency.
//     -16 loop-carried VGPRs; K prefetch + double-buffered P unchanged.

#define SLEN 2048
#define DK   32
#define NBH  48
#define PROW 40   // P-buffer row stride in bf16 (80 B, 16B-aligned)
#define NCH  32   // 32-key chunks per wave (half of 64)

typedef __attribute__((ext_vector_type(8))) short bf16x8;
typedef __attribute__((ext_vector_type(4))) float f32x4;

__device__ __forceinline__ unsigned pk2(float a, float b) {
    __hip_bfloat162 h = __float22bfloat162_rn(make_float2(a, b));
    union { __hip_bfloat162 h2; unsigned u; } cv; cv.h2 = h; return cv.u;
}

// ---- fused prep: K -> Kbf (frag order, even/odd interleave);
//                  V -> VTf (V^T frag order) --------------------------------
// Kbf frag ((bh*128 + t)*64 + l): t = 2c+tb, key = c*32 + 2*(l&15) + tb,
//   elems K[bh][key][(l>>4)*8 + j], j=0..7.
// VTf frag (((bh*64 + c)*2 + h)*64 + l): elems V[bh][c*32+(l>>4)*8+j][h*16+(l&15)].
__global__ __launch_bounds__(256)
void prep_kv(const float* __restrict__ K, const float* __restrict__ V,
             unsigned short* __restrict__ Kbf, unsigned short* __restrict__ VTf) {
    if (blockIdx.x < NBH * 32) {
        const int b  = blockIdx.x;
        const int bh = b >> 5, kg = b & 31;
        const int tl = threadIdx.x >> 6, l = threadIdx.x & 63;
        const int t  = kg * 4 + tl;
        const int c  = t >> 1, tb = t & 1;
        const int key = c * 32 + 2 * (l & 15) + tb;
        const float* src = K + ((size_t)bh * SLEN + key) * DK + (l >> 4) * 8;
        float4 a = *(const float4*)src;
        float4 b4 = *(const float4*)(src + 4);
        union { uint4 q; unsigned u[4]; } o;
        o.u[0] = pk2(a.x, a.y);  o.u[1] = pk2(a.z, a.w);
        o.u[2] = pk2(b4.x, b4.y); o.u[3] = pk2(b4.z, b4.w);
        *(uint4*)(Kbf + (((size_t)bh * 128 + t) * 64 + l) * 8) = o.q;
    } else {
        __shared__ float tile[32][33];
        const int b  = blockIdx.x - NBH * 32;
        const int bh = b >> 6, c = b & 63;
        const int t  = threadIdx.x;
        {
            const int row = t >> 3, c4 = (t & 7) * 4;
            float4 v4 = *(const float4*)(V + ((size_t)bh * SLEN + c * 32 + row) * DK + c4);
            tile[row][c4 + 0] = v4.x; tile[row][c4 + 1] = v4.y;
            tile[row][c4 + 2] = v4.z; tile[row][c4 + 3] = v4.w;
        }
        __syncthreads();
        const int h = t >> 7, l = (t >> 1) & 63, jh = t & 1;
        const int col = h * 16 + (l & 15);
        const int r0  = (l >> 4) * 8 + jh * 4;
        uint2 u;
        u.x = pk2(tile[r0 + 0][col], tile[r0 + 1][col]);
        u.y = pk2(tile[r0 + 2][col], tile[r0 + 3][col]);
        *(uint2*)(VTf + ((((size_t)bh * 64 + c) * 2 + h) * 64 + l) * 8 + jh * 4) = u;
    }
}

// ---- main: pipelined MFMA attention ----------------------------------------
__global__ __launch_bounds__(256, 6)
void attn_mfma(const float* __restrict__ Q, const unsigned short* __restrict__ Kbf,
               const unsigned short* __restrict__ VTf, float* __restrict__ Out) {
    __shared__ __align__(16) unsigned short Pbuf[4][2][16 * PROW];  // 10240 B
    __shared__ __align__(16) float Red[2][64][12];                  //  6144 B

    const int tid  = threadIdx.x;
    const int lane = tid & 63;
    const int wv   = tid >> 6;
    const int quad = lane >> 4;
    const int l16  = lane & 15;
    const int qi   = wv >> 1;          // which q-tile of the block's pair
    const int kh   = wv & 1;           // which key half (0: 0..1023, 1: 1024..2047)

    // XCD-aware head clustering: 6 heads per XCD.
    const int b   = blockIdx.x;        // grid = 3072
    const int xcd = b & 7;
    const int i   = b >> 3;            // 0..383
    const int bh  = xcd * 6 + (i % 6);
    const int qp  = i / 6;             // 0..63 q-tile pairs
    const int qbase = (qp * 2 + qi) * 16;

    // Q a-frag, scaled by (1/sqrt(32))*log2(e) -> log2-domain scores
    const float sc = 0.17677669529663687f * 1.4426950408889634f;
    const float* qp_ = Q + ((size_t)bh * SLEN + qbase + l16) * DK + quad * 8;
    float4 qa = *(const float4*)qp_;
    float4 qb = *(const float4*)(qp_ + 4);
    union { bf16x8 v; unsigned u[4]; } aQ;
    aQ.u[0] = pk2(qa.x * sc, qa.y * sc); aQ.u[1] = pk2(qa.z * sc, qa.w * sc);
    aQ.u[2] = pk2(qb.x * sc, qb.y * sc); aQ.u[3] = pk2(qb.z * sc, qb.w * sc);

    // frag streams for this wave's key half (chunk c: tiles at c*128 + {0,64})
    const bf16x8* kf = (const bf16x8*)Kbf + (size_t)bh * 8192 + (size_t)kh * 4096 + lane;
    const bf16x8* vf = (const bf16x8*)VTf + (size_t)bh * 8192 + (size_t)kh * 4096 + lane;

    f32x4 o0 = {0.f, 0.f, 0.f, 0.f};
    f32x4 o1 = {0.f, 0.f, 0.f, 0.f};
    f32x4 den = {0.f, 0.f, 0.f, 0.f};
    const f32x4 zero = {0.f, 0.f, 0.f, 0.f};

    unsigned short* pb  = &Pbuf[wv][0][0];
    unsigned*       pbw = (unsigned*)pb;

    auto exppack = [&](const f32x4& s0, const f32x4& s1, int buf) {
        unsigned* pw = pbw + buf * (16 * PROW / 2);
        #pragma unroll
        for (int r = 0; r < 4; ++r) {
            float e0  = __builtin_amdgcn_exp2f(s0[r]);
            float en0 = __builtin_amdgcn_exp2f(-s0[r]);
            float e1  = __builtin_amdgcn_exp2f(s1[r]);
            float en1 = __builtin_amdgcn_exp2f(-s1[r]);
            den[r] += (e0 + en0) + (e1 + en1);
            pw[(quad * 4 + r) * (PROW / 2) + l16] = pk2(e0 - en0, e1 - en1);
        }
    };
    auto readP = [&](int buf) -> bf16x8 {
        return *(const bf16x8*)(pb + buf * (16 * PROW) + l16 * PROW + quad * 8);
    };

    // ---- prologue: chunk 0 scores + P(0); preload k(1) ----
    bf16x8 ka = kf[0], kb = kf[64];
    f32x4 s0 = __builtin_amdgcn_mfma_f32_16x16x32_bf16(aQ.v, ka, zero, 0, 0, 0);
    f32x4 s1 = __builtin_amdgcn_mfma_f32_16x16x32_bf16(aQ.v, kb, zero, 0, 0, 0);
    ka = kf[128]; kb = kf[192];
    exppack(s0, s1, 0);

    // ---- steady state ----
    for (int c = 0; c < NCH - 1; ++c) {
        // scores(c+1) with K-frags loaded one iteration ago
        s0 = __builtin_amdgcn_mfma_f32_16x16x32_bf16(aQ.v, ka, zero, 0, 0, 0);
        s1 = __builtin_amdgcn_mfma_f32_16x16x32_bf16(aQ.v, kb, zero, 0, 0, 0);
        // prefetch k(c+2) (wrapped: tail re-loads chunk 0/1, harmless)
        const int c2 = (c + 2) & (NCH - 1);
        ka = kf[(size_t)c2 * 128]; kb = kf[(size_t)c2 * 128 + 64];
        // v(c): direct load, used ~250 cyc later (after readP + exppack)
        bf16x8 vc0 = vf[(size_t)c * 128];
        bf16x8 vc1 = vf[(size_t)c * 128 + 64];
        // read P(c) -- written last iteration, round-trip already complete
        bf16x8 aP = readP(c & 1);
        // exp/pack/write P(c+1) into the other buffer
        exppack(s0, s1, (c + 1) & 1);
        // PV(c)
        o0 = __builtin_amdgcn_mfma_f32_16x16x32_bf16(aP, vc0, o0, 0, 0, 0);
        o1 = __builtin_amdgcn_mfma_f32_16x16x32_bf16(aP, vc1, o1, 0, 0, 0);
    }
    // ---- epilogue: PV(last) ----
    {
        bf16x8 aP = readP((NCH - 1) & 1);
        bf16x8 vc0 = vf[(size_t)(NCH - 1) * 128];
        bf16x8 vc1 = vf[(size_t)(NCH - 1) * 128 + 64];
        o0 = __builtin_amdgcn_mfma_f32_16x16x32_bf16(aP, vc0, o0, 0, 0, 0);
        o1 = __builtin_amdgcn_mfma_f32_16x16x32_bf16(aP, vc1, o1, 0, 0, 0);
    }

    // den: reduce across the 16 key-column lanes of each quad group
    #pragma unroll
    for (int r = 0; r < 4; ++r) {
        den[r] += __shfl_xor(den[r], 1, 16);
        den[r] += __shfl_xor(den[r], 2, 16);
        den[r] += __shfl_xor(den[r], 4, 16);
        den[r] += __shfl_xor(den[r], 8, 16);
    }

    // cross-wave (key-half) combine
    if (kh == 1) {
        float* r = &Red[qi][lane][0];
        *(f32x4*)(r + 0) = o0;
        *(f32x4*)(r + 4) = o1;
        *(f32x4*)(r + 8) = den;
    }
    __syncthreads();
    if (kh == 0) {
        const float* r = &Red[qi][lane][0];
        f32x4 p0 = *(const f32x4*)(r + 0);
        f32x4 p1 = *(const f32x4*)(r + 4);
        f32x4 pd = *(const f32x4*)(r + 8);
        o0 += p0; o1 += p1; den += pd;

        float* outp = Out + ((size_t)bh * SLEN + qbase) * DK;
        #pragma unroll
        for (int rr = 0; rr < 4; ++rr) {
            float inv = 1.0f / den[rr];
            int q = quad * 4 + rr;
            outp[(size_t)q * DK + l16]      = o0[rr] * inv;
            outp[(size_t)q * DK + 16 + l16] = o1[rr] * inv;
        }
    }
}

extern "C" void kernel_launch(void* const* d_in, const int* in_sizes, int n_in,
                              void* d_out, int out_size, void* d_ws, size_t ws_size,
                              hipStream_t stream) {
    const float* Q = (const float*)d_in[0];
    const float* K = (const float*)d_in[1];
    const float* V = (const float*)d_in[2];
    // d_in[3] = attn_mask: no-op in reference, never read
    float* Out = (float*)d_out;
    unsigned short* Kbf = (unsigned short*)d_ws;                      // 6.29 MB
    unsigned short* VTf = Kbf + (size_t)NBH * SLEN * DK;              // 6.29 MB

    prep_kv<<<dim3(NBH * 32 + NBH * 64), dim3(256), 0, stream>>>(K, V, Kbf, VTf);
    attn_mfma<<<dim3(3072), dim3(256), 0, stream>>>(Q, Kbf, VTf, Out);
}